// Round 1
// baseline (590.233 us; speedup 1.0000x reference)
//
#include <hip/hip_runtime.h>
#include <hip/hip_bf16.h>
#include <math.h>

// Problem constants (fixed by setup_inputs)
#define Bq   8
#define Cc   5
#define Hh   512
#define Ww   512
#define HW   262144      // 512*512
#define NPIX 2097152     // 8*HW
#define CF   32
#define NROWS 4096       // B*H
#define MAXT 1024
#define MAXO 4096

// ws layout, element offsets (4-byte units). Region [0, Z_ELEMS) is zeroed each launch.
#define FO_ACC    0        // 18 floats: [0]ce [1]focal [2]grad [3..7]inter [8..12]psum [13..17]cnt
#define IO_ROWCNT 32       // int[4096] fg count per image-row
#define FO_ST     4128     // float[1024] sum exp(sim_t) per tiny row
#define FO_SO     5152     // float[1024] sum exp(sim_o) per tiny row
#define Z_ELEMS   6176
#define IO_PREFIX 6176     // int[4096] exclusive prefix of tiny counts per row
#define IO_SCAL   10272    // int[16]: [0]=cnt_tiny [1]=any_tiny [2..9]=tiny_img flags
#define IO_TIDX   10288    // int[1024]
#define IO_OIDX   11312    // int[4096]
#define FO_TEMB   15408    // float[1024*32]
#define FO_OEMB   48176    // float[4096*32]
#define FO_PRED   179248   // float[NPIX]
#define WS_ELEMS  2276400  // ~9.11 MB

__device__ __forceinline__ float wave_sum(float v) {
  #pragma unroll
  for (int off = 32; off > 0; off >>= 1) v += __shfl_xor(v, off);
  return v;
}

// K1: per-pixel softmax -> ce, focal, dice partials, pred_fg, per-row fg counts
__global__ __launch_bounds__(256) void k_main(const float* __restrict__ logits,
                                              const int* __restrict__ targets,
                                              float* __restrict__ wsf,
                                              int* __restrict__ wsi) {
  int tid = threadIdx.x;
  int idx = blockIdx.x * 256 + tid;
  int b = idx >> 18;
  int rem = idx & (HW - 1);
  const float* lp = logits + (size_t)b * (Cc * HW) + rem;
  float l0 = lp[0], l1 = lp[HW], l2 = lp[2 * HW], l3 = lp[3 * HW], l4 = lp[4 * HW];
  float m = fmaxf(fmaxf(fmaxf(l0, l1), fmaxf(l2, l3)), l4);
  float e0 = __expf(l0 - m), e1 = __expf(l1 - m), e2 = __expf(l2 - m),
        e3 = __expf(l3 - m), e4 = __expf(l4 - m);
  float se = e0 + e1 + e2 + e3 + e4;
  float inv = 1.0f / se;
  float p0 = e0 * inv, p1 = e1 * inv, p2 = e2 * inv, p3 = e3 * inv, p4 = e4 * inv;
  int t = targets[idx];
  float lt = t == 0 ? l0 : t == 1 ? l1 : t == 2 ? l2 : t == 3 ? l3 : l4;
  float pt = t == 0 ? p0 : t == 1 ? p1 : t == 2 ? p2 : t == 3 ? p3 : p4;
  float ce = __logf(se) + m - lt;                 // -log_softmax[target]
  float om = fminf(fmaxf(1.0f - pt, 0.0f), 1.0f);
  float focal = om * om * ce;                     // GAMMA = 2
  wsf[FO_PRED + idx] = p1;                        // probs[:, FG_IDX]
  if (t == 1) atomicAdd(&wsi[IO_ROWCNT + (idx >> 9)], 1);

  float acc[18];
  acc[0] = ce; acc[1] = focal; acc[2] = 0.0f;
  acc[3] = (t == 0) ? pt : 0.0f;
  acc[4] = (t == 1) ? pt : 0.0f;
  acc[5] = (t == 2) ? pt : 0.0f;
  acc[6] = (t == 3) ? pt : 0.0f;
  acc[7] = (t == 4) ? pt : 0.0f;
  acc[8] = p0; acc[9] = p1; acc[10] = p2; acc[11] = p3; acc[12] = p4;
  acc[13] = (t == 0) ? 1.0f : 0.0f;
  acc[14] = (t == 1) ? 1.0f : 0.0f;
  acc[15] = (t == 2) ? 1.0f : 0.0f;
  acc[16] = (t == 3) ? 1.0f : 0.0f;
  acc[17] = (t == 4) ? 1.0f : 0.0f;

  __shared__ float red[4][18];
  #pragma unroll
  for (int k = 0; k < 18; k++) acc[k] = wave_sum(acc[k]);
  int lane = tid & 63, wv = tid >> 6;
  if (lane == 0) {
    #pragma unroll
    for (int k = 0; k < 18; k++) red[wv][k] = acc[k];
  }
  __syncthreads();
  if (tid < 18) {
    float s = red[0][tid] + red[1][tid] + red[2][tid] + red[3][tid];
    atomicAdd(&wsf[FO_ACC + tid], s);
  }
}

// K2: Sobel |grad(pred_fg) - grad(target_fg)| sum (zero-padded 3x3, correlation)
__global__ __launch_bounds__(256) void k_sobel(const int* __restrict__ targets,
                                               const float* __restrict__ pred,
                                               float* __restrict__ wsf) {
  int tid = threadIdx.x;
  int idx = blockIdx.x * 256 + tid;
  int b = idx >> 18;
  int hw = idx & (HW - 1);
  int h = hw >> 9, w = hw & (Ww - 1);
  const float* pb = pred + (size_t)b * HW;
  const int* tb = targets + (size_t)b * HW;
  float pp[9], tf[9];
  #pragma unroll
  for (int dh = 0; dh < 3; dh++) {
    int hh = h + dh - 1;
    bool hin = (hh >= 0) & (hh < Hh);
    #pragma unroll
    for (int dw = 0; dw < 3; dw++) {
      int wc = w + dw - 1;
      bool in = hin & (wc >= 0) & (wc < Ww);
      float pv = 0.0f, tv = 0.0f;
      if (in) {
        int o = hh * Ww + wc;
        pv = pb[o];
        tv = (tb[o] > 0) ? 1.0f : 0.0f;
      }
      pp[dh * 3 + dw] = pv;
      tf[dh * 3 + dw] = tv;
    }
  }
  float gxp = (pp[2] + 2.0f * pp[5] + pp[8]) - (pp[0] + 2.0f * pp[3] + pp[6]);
  float gyp = (pp[6] + 2.0f * pp[7] + pp[8]) - (pp[0] + 2.0f * pp[1] + pp[2]);
  float gp = sqrtf(gxp * gxp + gyp * gyp + 1e-6f);
  float gxt = (tf[2] + 2.0f * tf[5] + tf[8]) - (tf[0] + 2.0f * tf[3] + tf[6]);
  float gyt = (tf[6] + 2.0f * tf[7] + tf[8]) - (tf[0] + 2.0f * tf[1] + tf[2]);
  float gt = sqrtf(gxt * gxt + gyt * gyt + 1e-6f);
  float v = fabsf(gp - gt);
  v = wave_sum(v);
  __shared__ float red[4];
  int lane = tid & 63, wv = tid >> 6;
  if (lane == 0) red[wv] = v;
  __syncthreads();
  if (tid == 0) atomicAdd(&wsf[2], red[0] + red[1] + red[2] + red[3]);
}

// K3: single block: tiny_img flags + exclusive prefix of tiny counts over 4096 rows
__global__ __launch_bounds__(256) void k_scan(int* __restrict__ wsi) {
  __shared__ int ssum[256];
  __shared__ int stimg[8];
  __shared__ int sc[256];
  int tid = threadIdx.x;
  int base = tid * 16;          // thread covers rows [base, base+16), within one image
  int loc[16];
  int s = 0;
  #pragma unroll
  for (int k = 0; k < 16; k++) { loc[k] = wsi[IO_ROWCNT + base + k]; s += loc[k]; }
  ssum[tid] = s;
  __syncthreads();
  if (tid < 8) {
    int tot = 0;
    for (int u = 0; u < 32; u++) tot += ssum[tid * 32 + u];
    stimg[tid] = (tot > 0 && tot <= 2048) ? 1 : 0;   // TINY_THRESH
  }
  __syncthreads();
  int timg = stimg[tid >> 5];
  int ms = timg ? s : 0;
  sc[tid] = ms;
  __syncthreads();
  for (int off = 1; off < 256; off <<= 1) {
    int add = (tid >= off) ? sc[tid - off] : 0;
    __syncthreads();
    sc[tid] += add;
    __syncthreads();
  }
  int run = sc[tid] - ms;       // exclusive prefix at this thread's first row
  #pragma unroll
  for (int k = 0; k < 16; k++) {
    wsi[IO_PREFIX + base + k] = run;
    run += timg ? loc[k] : 0;
  }
  if (tid == 255) wsi[IO_SCAL + 0] = sc[255];
  if (tid < 8) wsi[IO_SCAL + 2 + tid] = stimg[tid];
  if (tid == 0) {
    int anyf = 0;
    for (int u = 0; u < 8; u++) anyf |= stimg[u];
    wsi[IO_SCAL + 1] = anyf;
  }
}

// K4: ordered compaction — first MAXT tiny indices, first MAXO non-tiny indices
__global__ __launch_bounds__(512) void k_widx(const int* __restrict__ targets,
                                              int* __restrict__ wsi) {
  int r = blockIdx.x;
  int tid = threadIdx.x;
  int b = r >> 9;
  int timg = wsi[IO_SCAL + 2 + b];
  int trc = timg ? wsi[IO_ROWCNT + r] : 0;
  int p = wsi[IO_PREFIX + r];
  int q = (r << 9) - p;   // false count before this row
  bool need_t = (trc > 0) && (p < MAXT);
  bool need_o = (q < MAXO) && (trc < 512);
  if (!need_t && !need_o) return;
  int i = (r << 9) + tid;
  int t = targets[i];
  bool f = (timg != 0) && (t == 1);
  unsigned long long mask = __ballot(f ? 1 : 0);
  int lane = tid & 63, wv = tid >> 6;
  int lpfx = __popcll(mask & ((1ull << lane) - 1ull));
  __shared__ int wt[8];
  if (lane == 0) wt[wv] = __popcll(mask);
  __syncthreads();
  int woff = 0;
  for (int u = 0; u < wv; u++) woff += wt[u];
  int local = woff + lpfx;
  if (f) {
    int pos = p + local;
    if (pos < MAXT) wsi[IO_TIDX + pos] = i;
  } else {
    int fpos = q + (tid - local);
    if (fpos < MAXO) wsi[IO_OIDX + fpos] = i;
  }
}

// K5: gather + L2-normalize 32-dim feature rows (1024 tiny + 4096 other)
__global__ __launch_bounds__(256) void k_gather(const float* __restrict__ pf,
                                                const int* __restrict__ wsi,
                                                float* __restrict__ wsf) {
  int tid = threadIdx.x;
  int g = blockIdx.x * 8 + (tid >> 5);
  int lane = tid & 31;
  int cnt = wsi[IO_SCAL + 0];
  int cnt_t = cnt < MAXT ? cnt : MAXT;
  long cfal = (long)NPIX - (long)cnt;
  int cnt_o = cfal > MAXO ? MAXO : (int)cfal;
  int idx;
  float* dst;
  if (g < MAXT) {
    dst = wsf + FO_TEMB + (size_t)g * 32;
    idx = (g < cnt_t) ? wsi[IO_TIDX + g] : -1;
  } else {
    int go = g - MAXT;
    dst = wsf + FO_OEMB + (size_t)go * 32;
    idx = (go < cnt_o) ? wsi[IO_OIDX + go] : -1;
  }
  float v = 0.0f;
  if (idx >= 0) {
    int b = idx >> 18;
    int rem = idx & (HW - 1);
    v = pf[((size_t)b * CF + lane) * HW + rem];
  }
  float ss = v * v;
  #pragma unroll
  for (int off = 16; off > 0; off >>= 1) ss += __shfl_xor(ss, off, 32);
  float nrm = fmaxf(sqrtf(ss), 1e-12f);
  dst[lane] = v / nrm;
}

// K6: sim rows (1024) x cols (1024 t + 4096 o); plain-sum logsumexp partials.
// sim in [-10,10] since vectors are unit-norm, so exp() is safe without max-shift.
__global__ __launch_bounds__(256) void k_sim(float* __restrict__ wsf,
                                             const int* __restrict__ wsi) {
  int tid = threadIdx.x;
  int rb = blockIdx.x / 40;   // 0..3 row blocks of 256
  int cc = blockIdx.x % 40;   // 0..39 col chunks of 128
  int j = rb * 256 + tid;
  const float* temb = wsf + FO_TEMB;
  const float* oemb = wsf + FO_OEMB;
  float rv[32];
  const float4* r4 = (const float4*)(temb + (size_t)j * 32);
  #pragma unroll
  for (int k = 0; k < 8; k++) {
    float4 x = r4[k];
    rv[4 * k + 0] = x.x; rv[4 * k + 1] = x.y; rv[4 * k + 2] = x.z; rv[4 * k + 3] = x.w;
  }
  int cnt = wsi[IO_SCAL + 0];
  int cnt_t = cnt < MAXT ? cnt : MAXT;
  long cfal = (long)NPIX - (long)cnt;
  int cnt_o = cfal > MAXO ? MAXO : (int)cfal;
  int c0 = cc * 128;
  bool is_t = (c0 < MAXT);
  const float* cbase = is_t ? (temb + (size_t)c0 * 32) : (oemb + (size_t)(c0 - MAXT) * 32);
  int climit = is_t ? (cnt_t - c0) : (cnt_o - (c0 - MAXT));
  float s = 0.0f;
  for (int c = 0; c < 128; c++) {
    const float* cv = cbase + c * 32;  // wave-uniform address -> scalar loads
    float dot = 0.0f;
    #pragma unroll
    for (int k = 0; k < 32; k++) dot = fmaf(rv[k], cv[k], dot);
    bool masked = (c >= climit) || (is_t && ((c0 + c) == j));
    s += masked ? 0.0f : __expf(dot * 10.0f);   // 1/TEMP
  }
  atomicAdd(&wsf[(is_t ? FO_ST : FO_SO) + j], s);
}

// K7: single block: tiny loss reduce + cls contrastive + final assembly
__global__ __launch_bounds__(256) void k_final(const float* __restrict__ emb,
                                               const int* __restrict__ clst,
                                               const float* __restrict__ wsf,
                                               const int* __restrict__ wsi,
                                               float* __restrict__ out) {
  __shared__ float e[8 * 256];
  __shared__ float sdot[64];
  __shared__ float sred[4];
  __shared__ float s_pera[8];
  __shared__ int s_val[8];
  __shared__ float s_bce[8];
  int tid = threadIdx.x;

  // tiny loss: per[j] = log(st+so) - log(st), summed over valid rows
  int cnt = wsi[IO_SCAL + 0];
  int vt = cnt < MAXT ? cnt : MAXT;
  float ts = 0.0f;
  for (int jj = tid; jj < vt; jj += 256) {
    float a = wsf[FO_ST + jj];
    float c2 = wsf[FO_SO + jj];
    ts += __logf(a + c2) - __logf(a);
  }
  ts = wave_sum(ts);
  if ((tid & 63) == 0) sred[tid >> 6] = ts;
  __syncthreads();

  // cls embeddings: load + normalize
  for (int k = tid; k < 2048; k += 256) e[k] = emb[k];
  __syncthreads();
  int row = tid >> 5, lane = tid & 31;
  float ss = 0.0f;
  for (int k = lane; k < 256; k += 32) { float v = e[row * 256 + k]; ss += v * v; }
  #pragma unroll
  for (int off = 16; off > 0; off >>= 1) ss += __shfl_xor(ss, off, 32);
  float invn = 1.0f / fmaxf(sqrtf(ss), 1e-12f);
  for (int k = lane; k < 256; k += 32) e[row * 256 + k] *= invn;
  __syncthreads();
  if (tid < 64) {
    int i = tid >> 3, jc = tid & 7;
    float d = 0.0f;
    for (int k = 0; k < 256; k++) d = fmaf(e[i * 256 + k], e[jc * 256 + k], d);
    sdot[tid] = d;
  }
  __syncthreads();
  if (tid < 8) {
    int li = clst[tid];
    float spos = 0.0f, sall = 0.0f, bce = 0.0f;
    int haspos = 0;
    for (int jc = 0; jc < 8; jc++) {
      if (jc == tid) continue;
      float d = sdot[tid * 8 + jc];
      float ex = __expf(d * 10.0f);
      sall += ex;
      int same = (clst[jc] == li) ? 1 : 0;
      if (same) { spos += ex; haspos = 1; }
      float cosv = fminf(fmaxf(d, -1.0f), 1.0f);
      float p01 = (cosv + 1.0f) * 0.5f;
      float lpv = fmaxf(__logf(p01), -100.0f);
      float lnv = fmaxf(__logf(1.0f - p01), -100.0f);
      bce += -(same ? lpv : lnv);
    }
    s_pera[tid] = __logf(sall) - __logf(spos);  // -(lse_pos - lse_all)
    s_val[tid] = haspos;
    s_bce[tid] = bce;
  }
  __syncthreads();
  if (tid == 0) {
    int nv = 0;
    float sm = 0.0f, sb = 0.0f;
    for (int i = 0; i < 8; i++) {
      if (s_val[i]) { nv++; sm += s_pera[i]; }
      sb += s_bce[i];
    }
    float cls = (nv > 0) ? (sm / (float)nv) : (sb / 56.0f);
    float invN = 1.0f / (float)NPIX;
    float ce_l = wsf[0] * invN;
    float focal_l = wsf[1] * invN;
    float grad_l = wsf[2] * invN;
    float dsum = 0.0f;
    for (int c = 0; c < 5; c++)
      dsum += (2.0f * wsf[3 + c] + 1e-6f) / (wsf[8 + c] + wsf[13 + c] + 1e-6f);
    float dice_l = 1.0f - dsum * 0.2f;
    int anyt = wsi[IO_SCAL + 1];
    bool enabled = (anyt != 0) && (cnt >= 16);   // MIN_TINY
    float tiny_total = sred[0] + sred[1] + sred[2] + sred[3];
    int n_t = vt > 1 ? vt : 1;
    float tiny_l = enabled ? (tiny_total / (float)n_t) : 0.0f;
    out[0] = ce_l + dice_l + focal_l + grad_l + tiny_l + cls;
  }
}

extern "C" void kernel_launch(void* const* d_in, const int* in_sizes, int n_in,
                              void* d_out, int out_size, void* d_ws, size_t ws_size,
                              hipStream_t stream) {
  (void)in_sizes; (void)n_in; (void)out_size; (void)ws_size;
  const float* logits = (const float*)d_in[0];
  const int* targets = (const int*)d_in[1];
  const float* pf = (const float*)d_in[2];
  const float* emb = (const float*)d_in[3];
  const int* clst = (const int*)d_in[4];
  float* out = (float*)d_out;
  float* wsf = (float*)d_ws;
  int* wsi = (int*)d_ws;

  hipMemsetAsync(d_ws, 0, Z_ELEMS * 4, stream);
  hipLaunchKernelGGL(k_main, dim3(NPIX / 256), dim3(256), 0, stream, logits, targets, wsf, wsi);
  hipLaunchKernelGGL(k_sobel, dim3(NPIX / 256), dim3(256), 0, stream, targets, wsf + FO_PRED, wsf);
  hipLaunchKernelGGL(k_scan, dim3(1), dim3(256), 0, stream, wsi);
  hipLaunchKernelGGL(k_widx, dim3(NROWS), dim3(512), 0, stream, targets, wsi);
  hipLaunchKernelGGL(k_gather, dim3(5120 / 8), dim3(256), 0, stream, pf, wsi, wsf);
  hipLaunchKernelGGL(k_sim, dim3(160), dim3(256), 0, stream, wsf, wsi);
  hipLaunchKernelGGL(k_final, dim3(1), dim3(256), 0, stream, emb, clst, wsf, wsi, out);
}

// Round 2
// 439.255 us; speedup vs baseline: 1.3437x; 1.3437x over previous
//
#include <hip/hip_runtime.h>
#include <hip/hip_bf16.h>
#include <math.h>

// Problem constants (fixed by setup_inputs)
#define Bq   8
#define Cc   5
#define Hh   512
#define Ww   512
#define HW   262144      // 512*512
#define NPIX 2097152     // 8*HW
#define CF   32
#define NROWS 4096       // B*H
#define MAXT 1024
#define MAXO 4096
#define NBLK 512         // grid for k_main / k_sobel
#define GSTRIDE 131072   // NBLK*256
#define GITER 16         // NPIX / GSTRIDE

// ws layout, element offsets (4-byte units). Region [0, Z_ELEMS) is zeroed each launch.
#define FO_ACC    0        // 18 floats: [0]ce [1]focal [2]grad [3..7]inter [8..12]psum [13..17]cnt
#define IO_ROWCNT 32       // int[4096] fg count per image-row
#define FO_ST     4128     // float[1024] sum exp(sim_t) per tiny row
#define FO_SO     5152     // float[1024] sum exp(sim_o) per tiny row
#define Z_ELEMS   6176
#define IO_PREFIX 6176     // int[4096] exclusive prefix of tiny counts per row
#define IO_SCAL   10272    // int[16]: [0]=cnt_tiny [1]=any_tiny [2..9]=tiny_img flags
#define IO_TIDX   10288    // int[1024]
#define IO_OIDX   11312    // int[4096]
#define FO_TEMB   15408    // float[1024*32]
#define FO_OEMB   48176    // float[4096*32]
#define FO_PART   179248   // float[18*512]  per-block partials from k_main ([k][blk])
#define FO_GPART  188464   // float[512]     per-block partials from k_sobel
#define FO_PRED   188976   // float[NPIX]
#define WS_ELEMS  2286128  // ~9.14 MB

__device__ __forceinline__ float wave_sum(float v) {
  #pragma unroll
  for (int off = 32; off > 0; off >>= 1) v += __shfl_xor(v, off);
  return v;
}

// K1: grid-stride per-pixel softmax -> ce, focal, dice partials, pred_fg, per-row fg counts.
// Per-block partials stored (NO global float atomics); reduced later in k_scan.
__global__ __launch_bounds__(256) void k_main(const float* __restrict__ logits,
                                              const int* __restrict__ targets,
                                              float* __restrict__ wsf,
                                              int* __restrict__ wsi) {
  int tid = threadIdx.x;
  float acc[18];
  #pragma unroll
  for (int k = 0; k < 18; k++) acc[k] = 0.0f;
  int base = blockIdx.x * 256 + tid;
  for (int it = 0; it < GITER; it++) {
    int idx = base + it * GSTRIDE;
    int b = idx >> 18;
    int rem = idx & (HW - 1);
    const float* lp = logits + (size_t)b * (Cc * HW) + rem;
    float l0 = lp[0], l1 = lp[HW], l2 = lp[2 * HW], l3 = lp[3 * HW], l4 = lp[4 * HW];
    float m = fmaxf(fmaxf(fmaxf(l0, l1), fmaxf(l2, l3)), l4);
    float e0 = __expf(l0 - m), e1 = __expf(l1 - m), e2 = __expf(l2 - m),
          e3 = __expf(l3 - m), e4 = __expf(l4 - m);
    float se = e0 + e1 + e2 + e3 + e4;
    float inv = 1.0f / se;
    float p0 = e0 * inv, p1 = e1 * inv, p2 = e2 * inv, p3 = e3 * inv, p4 = e4 * inv;
    int t = targets[idx];
    float lt = t == 0 ? l0 : t == 1 ? l1 : t == 2 ? l2 : t == 3 ? l3 : l4;
    float pt = t == 0 ? p0 : t == 1 ? p1 : t == 2 ? p2 : t == 3 ? p3 : p4;
    float ce = __logf(se) + m - lt;                 // -log_softmax[target]
    float om = fminf(fmaxf(1.0f - pt, 0.0f), 1.0f);
    float focal = om * om * ce;                     // GAMMA = 2
    wsf[FO_PRED + idx] = p1;                        // probs[:, FG_IDX]
    // 64 consecutive lanes are always within one 512-wide row -> one atomic per wave
    unsigned long long mask = __ballot(t == 1);
    if (((tid & 63) == 0) && mask)
      atomicAdd(&wsi[IO_ROWCNT + (idx >> 9)], __popcll(mask));
    acc[0] += ce; acc[1] += focal;
    acc[3] += (t == 0) ? pt : 0.0f;
    acc[4] += (t == 1) ? pt : 0.0f;
    acc[5] += (t == 2) ? pt : 0.0f;
    acc[6] += (t == 3) ? pt : 0.0f;
    acc[7] += (t == 4) ? pt : 0.0f;
    acc[8] += p0; acc[9] += p1; acc[10] += p2; acc[11] += p3; acc[12] += p4;
    acc[13] += (t == 0) ? 1.0f : 0.0f;
    acc[14] += (t == 1) ? 1.0f : 0.0f;
    acc[15] += (t == 2) ? 1.0f : 0.0f;
    acc[16] += (t == 3) ? 1.0f : 0.0f;
    acc[17] += (t == 4) ? 1.0f : 0.0f;
  }
  __shared__ float red[4][18];
  #pragma unroll
  for (int k = 0; k < 18; k++) acc[k] = wave_sum(acc[k]);
  int lane = tid & 63, wv = tid >> 6;
  if (lane == 0) {
    #pragma unroll
    for (int k = 0; k < 18; k++) red[wv][k] = acc[k];
  }
  __syncthreads();
  if (tid < 18) {
    float s = red[0][tid] + red[1][tid] + red[2][tid] + red[3][tid];
    wsf[FO_PART + tid * NBLK + blockIdx.x] = s;
  }
}

// K2: grid-stride Sobel |grad(pred_fg) - grad(target_fg)|, per-block partial store
__global__ __launch_bounds__(256) void k_sobel(const int* __restrict__ targets,
                                               const float* __restrict__ pred,
                                               float* __restrict__ wsf) {
  int tid = threadIdx.x;
  float vsum = 0.0f;
  int base = blockIdx.x * 256 + tid;
  for (int it = 0; it < GITER; it++) {
    int idx = base + it * GSTRIDE;
    int b = idx >> 18;
    int hw = idx & (HW - 1);
    int h = hw >> 9, w = hw & (Ww - 1);
    const float* pb = pred + (size_t)b * HW;
    const int* tb = targets + (size_t)b * HW;
    float pp[9], tf[9];
    #pragma unroll
    for (int dh = 0; dh < 3; dh++) {
      int hh = h + dh - 1;
      bool hin = (hh >= 0) & (hh < Hh);
      #pragma unroll
      for (int dw = 0; dw < 3; dw++) {
        int wc = w + dw - 1;
        bool in = hin & (wc >= 0) & (wc < Ww);
        float pv = 0.0f, tv = 0.0f;
        if (in) {
          int o = hh * Ww + wc;
          pv = pb[o];
          tv = (tb[o] > 0) ? 1.0f : 0.0f;
        }
        pp[dh * 3 + dw] = pv;
        tf[dh * 3 + dw] = tv;
      }
    }
    float gxp = (pp[2] + 2.0f * pp[5] + pp[8]) - (pp[0] + 2.0f * pp[3] + pp[6]);
    float gyp = (pp[6] + 2.0f * pp[7] + pp[8]) - (pp[0] + 2.0f * pp[1] + pp[2]);
    float gp = sqrtf(gxp * gxp + gyp * gyp + 1e-6f);
    float gxt = (tf[2] + 2.0f * tf[5] + tf[8]) - (tf[0] + 2.0f * tf[3] + tf[6]);
    float gyt = (tf[6] + 2.0f * tf[7] + tf[8]) - (tf[0] + 2.0f * tf[1] + tf[2]);
    float gt = sqrtf(gxt * gxt + gyt * gyt + 1e-6f);
    vsum += fabsf(gp - gt);
  }
  vsum = wave_sum(vsum);
  __shared__ float red[4];
  int lane = tid & 63, wv = tid >> 6;
  if (lane == 0) red[wv] = vsum;
  __syncthreads();
  if (tid == 0) wsf[FO_GPART + blockIdx.x] = red[0] + red[1] + red[2] + red[3];
}

// K3: single block: reduce k_main/k_sobel partials; tiny_img flags; exclusive
// prefix of tiny counts over 4096 rows
__global__ __launch_bounds__(256) void k_scan(int* __restrict__ wsi,
                                              float* __restrict__ wsf) {
  __shared__ int ssum[256];
  __shared__ int stimg[8];
  __shared__ int sc[256];
  __shared__ float fred[4][18];
  __shared__ float gred[4];
  int tid = threadIdx.x;
  int lane = tid & 63, wv = tid >> 6;

  // --- reduce the 18 k_main partial arrays + sobel partials ---
  float ls[18];
  #pragma unroll
  for (int k = 0; k < 18; k++)
    ls[k] = wsf[FO_PART + k * NBLK + tid] + wsf[FO_PART + k * NBLK + 256 + tid];
  #pragma unroll
  for (int k = 0; k < 18; k++) ls[k] = wave_sum(ls[k]);
  if (lane == 0) {
    #pragma unroll
    for (int k = 0; k < 18; k++) fred[wv][k] = ls[k];
  }
  float g = wsf[FO_GPART + tid] + wsf[FO_GPART + 256 + tid];
  g = wave_sum(g);
  if (lane == 0) gred[wv] = g;
  __syncthreads();
  if (tid < 18) {
    float s = fred[0][tid] + fred[1][tid] + fred[2][tid] + fred[3][tid];
    if (tid == 2) s = gred[0] + gred[1] + gred[2] + gred[3];
    wsf[FO_ACC + tid] = s;
  }

  // --- row scan ---
  int base = tid * 16;          // thread covers rows [base, base+16), within one image
  int loc[16];
  int s = 0;
  #pragma unroll
  for (int k = 0; k < 16; k++) { loc[k] = wsi[IO_ROWCNT + base + k]; s += loc[k]; }
  ssum[tid] = s;
  __syncthreads();
  if (tid < 8) {
    int tot = 0;
    for (int u = 0; u < 32; u++) tot += ssum[tid * 32 + u];
    stimg[tid] = (tot > 0 && tot <= 2048) ? 1 : 0;   // TINY_THRESH
  }
  __syncthreads();
  int timg = stimg[tid >> 5];
  int ms = timg ? s : 0;
  sc[tid] = ms;
  __syncthreads();
  for (int off = 1; off < 256; off <<= 1) {
    int add = (tid >= off) ? sc[tid - off] : 0;
    __syncthreads();
    sc[tid] += add;
    __syncthreads();
  }
  int run = sc[tid] - ms;       // exclusive prefix at this thread's first row
  #pragma unroll
  for (int k = 0; k < 16; k++) {
    wsi[IO_PREFIX + base + k] = run;
    run += timg ? loc[k] : 0;
  }
  if (tid == 255) wsi[IO_SCAL + 0] = sc[255];
  if (tid < 8) wsi[IO_SCAL + 2 + tid] = stimg[tid];
  if (tid == 0) {
    int anyf = 0;
    for (int u = 0; u < 8; u++) anyf |= stimg[u];
    wsi[IO_SCAL + 1] = anyf;
  }
}

// K4: ordered compaction — first MAXT tiny indices, first MAXO non-tiny indices
__global__ __launch_bounds__(512) void k_widx(const int* __restrict__ targets,
                                              int* __restrict__ wsi) {
  int r = blockIdx.x;
  int tid = threadIdx.x;
  int b = r >> 9;
  int timg = wsi[IO_SCAL + 2 + b];
  int trc = timg ? wsi[IO_ROWCNT + r] : 0;
  int p = wsi[IO_PREFIX + r];
  int q = (r << 9) - p;   // false count before this row
  bool need_t = (trc > 0) && (p < MAXT);
  bool need_o = (q < MAXO) && (trc < 512);
  if (!need_t && !need_o) return;
  int i = (r << 9) + tid;
  int t = targets[i];
  bool f = (timg != 0) && (t == 1);
  unsigned long long mask = __ballot(f ? 1 : 0);
  int lane = tid & 63, wv = tid >> 6;
  int lpfx = __popcll(mask & ((1ull << lane) - 1ull));
  __shared__ int wt[8];
  if (lane == 0) wt[wv] = __popcll(mask);
  __syncthreads();
  int woff = 0;
  for (int u = 0; u < wv; u++) woff += wt[u];
  int local = woff + lpfx;
  if (f) {
    int pos = p + local;
    if (pos < MAXT) wsi[IO_TIDX + pos] = i;
  } else {
    int fpos = q + (tid - local);
    if (fpos < MAXO) wsi[IO_OIDX + fpos] = i;
  }
}

// K5: gather + L2-normalize 32-dim feature rows (1024 tiny + 4096 other)
__global__ __launch_bounds__(256) void k_gather(const float* __restrict__ pf,
                                                const int* __restrict__ wsi,
                                                float* __restrict__ wsf) {
  int tid = threadIdx.x;
  int g = blockIdx.x * 8 + (tid >> 5);
  int lane = tid & 31;
  int cnt = wsi[IO_SCAL + 0];
  int cnt_t = cnt < MAXT ? cnt : MAXT;
  long cfal = (long)NPIX - (long)cnt;
  int cnt_o = cfal > MAXO ? MAXO : (int)cfal;
  int idx;
  float* dst;
  if (g < MAXT) {
    dst = wsf + FO_TEMB + (size_t)g * 32;
    idx = (g < cnt_t) ? wsi[IO_TIDX + g] : -1;
  } else {
    int go = g - MAXT;
    dst = wsf + FO_OEMB + (size_t)go * 32;
    idx = (go < cnt_o) ? wsi[IO_OIDX + go] : -1;
  }
  float v = 0.0f;
  if (idx >= 0) {
    int b = idx >> 18;
    int rem = idx & (HW - 1);
    v = pf[((size_t)b * CF + lane) * HW + rem];
  }
  float ss = v * v;
  #pragma unroll
  for (int off = 16; off > 0; off >>= 1) ss += __shfl_xor(ss, off, 32);
  float nrm = fmaxf(sqrtf(ss), 1e-12f);
  dst[lane] = v / nrm;
}

// K6: sim rows (1024) x cols (1024 t + 4096 o); plain-sum logsumexp partials.
// sim in [-10,10] since vectors are unit-norm, so exp() is safe without max-shift.
__global__ __launch_bounds__(256) void k_sim(float* __restrict__ wsf,
                                             const int* __restrict__ wsi) {
  int tid = threadIdx.x;
  int rb = blockIdx.x / 40;   // 0..3 row blocks of 256
  int cc = blockIdx.x % 40;   // 0..39 col chunks of 128
  int j = rb * 256 + tid;
  const float* temb = wsf + FO_TEMB;
  const float* oemb = wsf + FO_OEMB;
  float rv[32];
  const float4* r4 = (const float4*)(temb + (size_t)j * 32);
  #pragma unroll
  for (int k = 0; k < 8; k++) {
    float4 x = r4[k];
    rv[4 * k + 0] = x.x; rv[4 * k + 1] = x.y; rv[4 * k + 2] = x.z; rv[4 * k + 3] = x.w;
  }
  int cnt = wsi[IO_SCAL + 0];
  int cnt_t = cnt < MAXT ? cnt : MAXT;
  long cfal = (long)NPIX - (long)cnt;
  int cnt_o = cfal > MAXO ? MAXO : (int)cfal;
  int c0 = cc * 128;
  bool is_t = (c0 < MAXT);
  const float* cbase = is_t ? (temb + (size_t)c0 * 32) : (oemb + (size_t)(c0 - MAXT) * 32);
  int climit = is_t ? (cnt_t - c0) : (cnt_o - (c0 - MAXT));
  float s = 0.0f;
  for (int c = 0; c < 128; c++) {
    const float* cv = cbase + c * 32;  // wave-uniform address -> scalar loads
    float dot = 0.0f;
    #pragma unroll
    for (int k = 0; k < 32; k++) dot = fmaf(rv[k], cv[k], dot);
    bool masked = (c >= climit) || (is_t && ((c0 + c) == j));
    s += masked ? 0.0f : __expf(dot * 10.0f);   // 1/TEMP
  }
  atomicAdd(&wsf[(is_t ? FO_ST : FO_SO) + j], s);
}

// K7: single block: tiny loss reduce + cls contrastive + final assembly
__global__ __launch_bounds__(256) void k_final(const float* __restrict__ emb,
                                               const int* __restrict__ clst,
                                               const float* __restrict__ wsf,
                                               const int* __restrict__ wsi,
                                               float* __restrict__ out) {
  __shared__ float e[8 * 256];
  __shared__ float sdot[64];
  __shared__ float sred[4];
  __shared__ float s_pera[8];
  __shared__ int s_val[8];
  __shared__ float s_bce[8];
  int tid = threadIdx.x;

  // tiny loss: per[j] = log(st+so) - log(st), summed over valid rows
  int cnt = wsi[IO_SCAL + 0];
  int vt = cnt < MAXT ? cnt : MAXT;
  float ts = 0.0f;
  for (int jj = tid; jj < vt; jj += 256) {
    float a = wsf[FO_ST + jj];
    float c2 = wsf[FO_SO + jj];
    ts += __logf(a + c2) - __logf(a);
  }
  ts = wave_sum(ts);
  if ((tid & 63) == 0) sred[tid >> 6] = ts;
  __syncthreads();

  // cls embeddings: load + normalize
  for (int k = tid; k < 2048; k += 256) e[k] = emb[k];
  __syncthreads();
  int row = tid >> 5, lane = tid & 31;
  float ss = 0.0f;
  for (int k = lane; k < 256; k += 32) { float v = e[row * 256 + k]; ss += v * v; }
  #pragma unroll
  for (int off = 16; off > 0; off >>= 1) ss += __shfl_xor(ss, off, 32);
  float invn = 1.0f / fmaxf(sqrtf(ss), 1e-12f);
  for (int k = lane; k < 256; k += 32) e[row * 256 + k] *= invn;
  __syncthreads();
  if (tid < 64) {
    int i = tid >> 3, jc = tid & 7;
    float d = 0.0f;
    for (int k = 0; k < 256; k++) d = fmaf(e[i * 256 + k], e[jc * 256 + k], d);
    sdot[tid] = d;
  }
  __syncthreads();
  if (tid < 8) {
    int li = clst[tid];
    float spos = 0.0f, sall = 0.0f, bce = 0.0f;
    int haspos = 0;
    for (int jc = 0; jc < 8; jc++) {
      if (jc == tid) continue;
      float d = sdot[tid * 8 + jc];
      float ex = __expf(d * 10.0f);
      sall += ex;
      int same = (clst[jc] == li) ? 1 : 0;
      if (same) { spos += ex; haspos = 1; }
      float cosv = fminf(fmaxf(d, -1.0f), 1.0f);
      float p01 = (cosv + 1.0f) * 0.5f;
      float lpv = fmaxf(__logf(p01), -100.0f);
      float lnv = fmaxf(__logf(1.0f - p01), -100.0f);
      bce += -(same ? lpv : lnv);
    }
    s_pera[tid] = __logf(sall) - __logf(spos);  // -(lse_pos - lse_all)
    s_val[tid] = haspos;
    s_bce[tid] = bce;
  }
  __syncthreads();
  if (tid == 0) {
    int nv = 0;
    float sm = 0.0f, sb = 0.0f;
    for (int i = 0; i < 8; i++) {
      if (s_val[i]) { nv++; sm += s_pera[i]; }
      sb += s_bce[i];
    }
    float cls = (nv > 0) ? (sm / (float)nv) : (sb / 56.0f);
    float invN = 1.0f / (float)NPIX;
    float ce_l = wsf[0] * invN;
    float focal_l = wsf[1] * invN;
    float grad_l = wsf[2] * invN;
    float dsum = 0.0f;
    for (int c = 0; c < 5; c++)
      dsum += (2.0f * wsf[3 + c] + 1e-6f) / (wsf[8 + c] + wsf[13 + c] + 1e-6f);
    float dice_l = 1.0f - dsum * 0.2f;
    int anyt = wsi[IO_SCAL + 1];
    bool enabled = (anyt != 0) && (cnt >= 16);   // MIN_TINY
    float tiny_total = sred[0] + sred[1] + sred[2] + sred[3];
    int n_t = vt > 1 ? vt : 1;
    float tiny_l = enabled ? (tiny_total / (float)n_t) : 0.0f;
    out[0] = ce_l + dice_l + focal_l + grad_l + tiny_l + cls;
  }
}

extern "C" void kernel_launch(void* const* d_in, const int* in_sizes, int n_in,
                              void* d_out, int out_size, void* d_ws, size_t ws_size,
                              hipStream_t stream) {
  (void)in_sizes; (void)n_in; (void)out_size; (void)ws_size;
  const float* logits = (const float*)d_in[0];
  const int* targets = (const int*)d_in[1];
  const float* pf = (const float*)d_in[2];
  const float* emb = (const float*)d_in[3];
  const int* clst = (const int*)d_in[4];
  float* out = (float*)d_out;
  float* wsf = (float*)d_ws;
  int* wsi = (int*)d_ws;

  hipMemsetAsync(d_ws, 0, Z_ELEMS * 4, stream);
  hipLaunchKernelGGL(k_main, dim3(NBLK), dim3(256), 0, stream, logits, targets, wsf, wsi);
  hipLaunchKernelGGL(k_sobel, dim3(NBLK), dim3(256), 0, stream, targets, wsf + FO_PRED, wsf);
  hipLaunchKernelGGL(k_scan, dim3(1), dim3(256), 0, stream, wsi, wsf);
  hipLaunchKernelGGL(k_widx, dim3(NROWS), dim3(512), 0, stream, targets, wsi);
  hipLaunchKernelGGL(k_gather, dim3(5120 / 8), dim3(256), 0, stream, pf, wsi, wsf);
  hipLaunchKernelGGL(k_sim, dim3(160), dim3(256), 0, stream, wsf, wsi);
  hipLaunchKernelGGL(k_final, dim3(1), dim3(256), 0, stream, emb, clst, wsf, wsi, out);
}

// Round 3
// 392.454 us; speedup vs baseline: 1.5040x; 1.1193x over previous
//
#include <hip/hip_runtime.h>
#include <hip/hip_bf16.h>
#include <math.h>

// Problem constants (fixed by setup_inputs)
#define Bq   8
#define Cc   5
#define Hh   512
#define Ww   512
#define HW   262144      // 512*512
#define NPIX 2097152     // 8*HW
#define CF   32
#define NROWS 4096       // B*H
#define MAXT 1024
#define MAXO 4096
#define NBLK 1024        // grid for k_main / k_sobel (4 blocks/CU)
#define GSTRIDE 262144   // NBLK*256
#define GITER 8          // NPIX / GSTRIDE

// ws layout, element offsets (4-byte units). Region [0, Z_ELEMS) is zeroed each launch.
#define FO_ACC    0        // 18 floats: [0]ce [1]focal [2]grad [3..7]inter [8..12]psum [13..17]cnt
#define IO_ROWCNT 32       // int[4096] fg count per image-row
#define FO_ST     4128     // float[1024] sum exp(sim_t) per tiny row
#define FO_SO     5152     // float[1024] sum exp(sim_o) per tiny row
#define Z_ELEMS   6176
#define IO_PREFIX 6176     // int[4096] exclusive prefix of tiny counts per row
#define IO_SCAL   10272    // int[16]: [0]=cnt_tiny [1]=any_tiny [2..9]=tiny_img flags
#define IO_TIDX   10288    // int[1024]
#define IO_OIDX   11312    // int[4096]
#define FO_TEMB   15408    // float[1024*32]
#define FO_OEMB   48176    // float[4096*32]
#define FO_PART   179248   // float[18*1024]  per-block partials from k_main ([k][blk])
#define FO_GPART  197680   // float[1024]     per-block partials from k_sobel
#define FO_PRED   198704   // float[NPIX]
#define WS_ELEMS  2295856  // ~9.2 MB

__device__ __forceinline__ float wave_sum(float v) {
  #pragma unroll
  for (int off = 32; off > 0; off >>= 1) v += __shfl_xor(v, off);
  return v;
}

// K1: grid-stride per-pixel softmax -> ce, focal, dice partials, pred_fg, per-row fg counts.
// Per-block partials stored (NO global float atomics); reduced later in k_scan.
__global__ __launch_bounds__(256) void k_main(const float* __restrict__ logits,
                                              const int* __restrict__ targets,
                                              float* __restrict__ wsf,
                                              int* __restrict__ wsi) {
  int tid = threadIdx.x;
  float acc[18];
  #pragma unroll
  for (int k = 0; k < 18; k++) acc[k] = 0.0f;
  int base = blockIdx.x * 256 + tid;
  for (int it = 0; it < GITER; it++) {
    int idx = base + it * GSTRIDE;
    int b = idx >> 18;
    int rem = idx & (HW - 1);
    const float* lp = logits + (size_t)b * (Cc * HW) + rem;
    float l0 = lp[0], l1 = lp[HW], l2 = lp[2 * HW], l3 = lp[3 * HW], l4 = lp[4 * HW];
    float m = fmaxf(fmaxf(fmaxf(l0, l1), fmaxf(l2, l3)), l4);
    float e0 = __expf(l0 - m), e1 = __expf(l1 - m), e2 = __expf(l2 - m),
          e3 = __expf(l3 - m), e4 = __expf(l4 - m);
    float se = e0 + e1 + e2 + e3 + e4;
    float inv = 1.0f / se;
    float p0 = e0 * inv, p1 = e1 * inv, p2 = e2 * inv, p3 = e3 * inv, p4 = e4 * inv;
    int t = targets[idx];
    float lt = t == 0 ? l0 : t == 1 ? l1 : t == 2 ? l2 : t == 3 ? l3 : l4;
    float pt = t == 0 ? p0 : t == 1 ? p1 : t == 2 ? p2 : t == 3 ? p3 : p4;
    float ce = __logf(se) + m - lt;                 // -log_softmax[target]
    float om = fminf(fmaxf(1.0f - pt, 0.0f), 1.0f);
    float focal = om * om * ce;                     // GAMMA = 2
    wsf[FO_PRED + idx] = p1;                        // probs[:, FG_IDX]
    // 64 consecutive lanes are always within one 512-wide row -> one atomic per wave
    unsigned long long mask = __ballot(t == 1);
    if (((tid & 63) == 0) && mask)
      atomicAdd(&wsi[IO_ROWCNT + (idx >> 9)], __popcll(mask));
    acc[0] += ce; acc[1] += focal;
    acc[3] += (t == 0) ? pt : 0.0f;
    acc[4] += (t == 1) ? pt : 0.0f;
    acc[5] += (t == 2) ? pt : 0.0f;
    acc[6] += (t == 3) ? pt : 0.0f;
    acc[7] += (t == 4) ? pt : 0.0f;
    acc[8] += p0; acc[9] += p1; acc[10] += p2; acc[11] += p3; acc[12] += p4;
    acc[13] += (t == 0) ? 1.0f : 0.0f;
    acc[14] += (t == 1) ? 1.0f : 0.0f;
    acc[15] += (t == 2) ? 1.0f : 0.0f;
    acc[16] += (t == 3) ? 1.0f : 0.0f;
    acc[17] += (t == 4) ? 1.0f : 0.0f;
  }
  __shared__ float red[4][18];
  #pragma unroll
  for (int k = 0; k < 18; k++) acc[k] = wave_sum(acc[k]);
  int lane = tid & 63, wv = tid >> 6;
  if (lane == 0) {
    #pragma unroll
    for (int k = 0; k < 18; k++) red[wv][k] = acc[k];
  }
  __syncthreads();
  if (tid < 18) {
    float s = red[0][tid] + red[1][tid] + red[2][tid] + red[3][tid];
    wsf[FO_PART + tid * NBLK + blockIdx.x] = s;
  }
}

// K2: grid-stride Sobel |grad(pred_fg) - grad(target_fg)|, per-block partial store
__global__ __launch_bounds__(256) void k_sobel(const int* __restrict__ targets,
                                               const float* __restrict__ pred,
                                               float* __restrict__ wsf) {
  int tid = threadIdx.x;
  float vsum = 0.0f;
  int base = blockIdx.x * 256 + tid;
  for (int it = 0; it < GITER; it++) {
    int idx = base + it * GSTRIDE;
    int b = idx >> 18;
    int hw = idx & (HW - 1);
    int h = hw >> 9, w = hw & (Ww - 1);
    const float* pb = pred + (size_t)b * HW;
    const int* tb = targets + (size_t)b * HW;
    float pp[9], tf[9];
    #pragma unroll
    for (int dh = 0; dh < 3; dh++) {
      int hh = h + dh - 1;
      bool hin = (hh >= 0) & (hh < Hh);
      #pragma unroll
      for (int dw = 0; dw < 3; dw++) {
        int wc = w + dw - 1;
        bool in = hin & (wc >= 0) & (wc < Ww);
        float pv = 0.0f, tv = 0.0f;
        if (in) {
          int o = hh * Ww + wc;
          pv = pb[o];
          tv = (tb[o] > 0) ? 1.0f : 0.0f;
        }
        pp[dh * 3 + dw] = pv;
        tf[dh * 3 + dw] = tv;
      }
    }
    float gxp = (pp[2] + 2.0f * pp[5] + pp[8]) - (pp[0] + 2.0f * pp[3] + pp[6]);
    float gyp = (pp[6] + 2.0f * pp[7] + pp[8]) - (pp[0] + 2.0f * pp[1] + pp[2]);
    float gp = sqrtf(gxp * gxp + gyp * gyp + 1e-6f);
    float gxt = (tf[2] + 2.0f * tf[5] + tf[8]) - (tf[0] + 2.0f * tf[3] + tf[6]);
    float gyt = (tf[6] + 2.0f * tf[7] + tf[8]) - (tf[0] + 2.0f * tf[1] + tf[2]);
    float gt = sqrtf(gxt * gxt + gyt * gyt + 1e-6f);
    vsum += fabsf(gp - gt);
  }
  vsum = wave_sum(vsum);
  __shared__ float red[4];
  int lane = tid & 63, wv = tid >> 6;
  if (lane == 0) red[wv] = vsum;
  __syncthreads();
  if (tid == 0) wsf[FO_GPART + blockIdx.x] = red[0] + red[1] + red[2] + red[3];
}

// K3: single block: reduce k_main/k_sobel partials; tiny_img flags; exclusive
// prefix of tiny counts over 4096 rows
__global__ __launch_bounds__(256) void k_scan(int* __restrict__ wsi,
                                              float* __restrict__ wsf) {
  __shared__ int ssum[256];
  __shared__ int stimg[8];
  __shared__ int sc[256];
  __shared__ float fred[4][18];
  __shared__ float gred[4];
  int tid = threadIdx.x;
  int lane = tid & 63, wv = tid >> 6;

  // --- reduce the 18 k_main partial arrays + sobel partials ---
  float ls[18];
  #pragma unroll
  for (int k = 0; k < 18; k++) {
    const float* p = wsf + FO_PART + k * NBLK + tid;
    ls[k] = p[0] + p[256] + p[512] + p[768];
  }
  #pragma unroll
  for (int k = 0; k < 18; k++) ls[k] = wave_sum(ls[k]);
  if (lane == 0) {
    #pragma unroll
    for (int k = 0; k < 18; k++) fred[wv][k] = ls[k];
  }
  {
    const float* p = wsf + FO_GPART + tid;
    float g = p[0] + p[256] + p[512] + p[768];
    g = wave_sum(g);
    if (lane == 0) gred[wv] = g;
  }
  __syncthreads();
  if (tid < 18) {
    float s = fred[0][tid] + fred[1][tid] + fred[2][tid] + fred[3][tid];
    if (tid == 2) s = gred[0] + gred[1] + gred[2] + gred[3];
    wsf[FO_ACC + tid] = s;
  }

  // --- row scan ---
  int base = tid * 16;          // thread covers rows [base, base+16), within one image
  int loc[16];
  int s = 0;
  #pragma unroll
  for (int k = 0; k < 16; k++) { loc[k] = wsi[IO_ROWCNT + base + k]; s += loc[k]; }
  ssum[tid] = s;
  __syncthreads();
  if (tid < 8) {
    int tot = 0;
    for (int u = 0; u < 32; u++) tot += ssum[tid * 32 + u];
    stimg[tid] = (tot > 0 && tot <= 2048) ? 1 : 0;   // TINY_THRESH
  }
  __syncthreads();
  int timg = stimg[tid >> 5];
  int ms = timg ? s : 0;
  sc[tid] = ms;
  __syncthreads();
  for (int off = 1; off < 256; off <<= 1) {
    int add = (tid >= off) ? sc[tid - off] : 0;
    __syncthreads();
    sc[tid] += add;
    __syncthreads();
  }
  int run = sc[tid] - ms;       // exclusive prefix at this thread's first row
  #pragma unroll
  for (int k = 0; k < 16; k++) {
    wsi[IO_PREFIX + base + k] = run;
    run += timg ? loc[k] : 0;
  }
  if (tid == 255) wsi[IO_SCAL + 0] = sc[255];
  if (tid < 8) wsi[IO_SCAL + 2 + tid] = stimg[tid];
  if (tid == 0) {
    int anyf = 0;
    for (int u = 0; u < 8; u++) anyf |= stimg[u];
    wsi[IO_SCAL + 1] = anyf;
  }
}

// K4: ordered compaction — first MAXT tiny indices, first MAXO non-tiny indices
__global__ __launch_bounds__(512) void k_widx(const int* __restrict__ targets,
                                              int* __restrict__ wsi) {
  int r = blockIdx.x;
  int tid = threadIdx.x;
  int b = r >> 9;
  int timg = wsi[IO_SCAL + 2 + b];
  int trc = timg ? wsi[IO_ROWCNT + r] : 0;
  int p = wsi[IO_PREFIX + r];
  int q = (r << 9) - p;   // false count before this row
  bool need_t = (trc > 0) && (p < MAXT);
  bool need_o = (q < MAXO) && (trc < 512);
  if (!need_t && !need_o) return;
  int i = (r << 9) + tid;
  int t = targets[i];
  bool f = (timg != 0) && (t == 1);
  unsigned long long mask = __ballot(f ? 1 : 0);
  int lane = tid & 63, wv = tid >> 6;
  int lpfx = __popcll(mask & ((1ull << lane) - 1ull));
  __shared__ int wt[8];
  if (lane == 0) wt[wv] = __popcll(mask);
  __syncthreads();
  int woff = 0;
  for (int u = 0; u < wv; u++) woff += wt[u];
  int local = woff + lpfx;
  if (f) {
    int pos = p + local;
    if (pos < MAXT) wsi[IO_TIDX + pos] = i;
  } else {
    int fpos = q + (tid - local);
    if (fpos < MAXO) wsi[IO_OIDX + fpos] = i;
  }
}

// K5: gather + L2-normalize 32-dim feature rows (1024 tiny + 4096 other)
__global__ __launch_bounds__(256) void k_gather(const float* __restrict__ pf,
                                                const int* __restrict__ wsi,
                                                float* __restrict__ wsf) {
  int tid = threadIdx.x;
  int g = blockIdx.x * 8 + (tid >> 5);
  int lane = tid & 31;
  int cnt = wsi[IO_SCAL + 0];
  int cnt_t = cnt < MAXT ? cnt : MAXT;
  long cfal = (long)NPIX - (long)cnt;
  int cnt_o = cfal > MAXO ? MAXO : (int)cfal;
  int idx;
  float* dst;
  if (g < MAXT) {
    dst = wsf + FO_TEMB + (size_t)g * 32;
    idx = (g < cnt_t) ? wsi[IO_TIDX + g] : -1;
  } else {
    int go = g - MAXT;
    dst = wsf + FO_OEMB + (size_t)go * 32;
    idx = (go < cnt_o) ? wsi[IO_OIDX + go] : -1;
  }
  float v = 0.0f;
  if (idx >= 0) {
    int b = idx >> 18;
    int rem = idx & (HW - 1);
    v = pf[((size_t)b * CF + lane) * HW + rem];
  }
  float ss = v * v;
  #pragma unroll
  for (int off = 16; off > 0; off >>= 1) ss += __shfl_xor(ss, off, 32);
  float nrm = fmaxf(sqrtf(ss), 1e-12f);
  dst[lane] = v / nrm;
}

// K6: sim rows (1024) x cols (1024 t + 4096 o); plain-sum logsumexp partials.
// sim in [-10,10] since vectors are unit-norm, so exp() is safe without max-shift.
// 4-col unroll: 4 independent FMA chains, 512 B of uniform loads in flight.
__global__ __launch_bounds__(256) void k_sim(float* __restrict__ wsf,
                                             const int* __restrict__ wsi) {
  int tid = threadIdx.x;
  int rb = blockIdx.x / 80;   // 0..3 row blocks of 256
  int cc = blockIdx.x % 80;   // 0..79 col chunks of 64
  int j = rb * 256 + tid;
  const float* temb = wsf + FO_TEMB;
  const float* oemb = wsf + FO_OEMB;
  float rv[32];
  const float4* r4 = (const float4*)(temb + (size_t)j * 32);
  #pragma unroll
  for (int k = 0; k < 8; k++) {
    float4 x = r4[k];
    rv[4 * k + 0] = x.x; rv[4 * k + 1] = x.y; rv[4 * k + 2] = x.z; rv[4 * k + 3] = x.w;
  }
  int cnt = wsi[IO_SCAL + 0];
  int cnt_t = cnt < MAXT ? cnt : MAXT;
  long cfal = (long)NPIX - (long)cnt;
  int cnt_o = cfal > MAXO ? MAXO : (int)cfal;
  int c0 = cc * 64;
  bool is_t = (c0 < MAXT);
  const float* cbase = is_t ? (temb + (size_t)c0 * 32) : (oemb + (size_t)(c0 - MAXT) * 32);
  int climit = is_t ? (cnt_t - c0) : (cnt_o - (c0 - MAXT));
  float s = 0.0f;
  for (int c = 0; c < 64; c += 4) {
    const float* cv0 = cbase + (c + 0) * 32;
    const float* cv1 = cbase + (c + 1) * 32;
    const float* cv2 = cbase + (c + 2) * 32;
    const float* cv3 = cbase + (c + 3) * 32;
    float d0 = 0.0f, d1 = 0.0f, d2 = 0.0f, d3 = 0.0f;
    #pragma unroll
    for (int k = 0; k < 32; k++) {
      float r = rv[k];
      d0 = fmaf(r, cv0[k], d0);
      d1 = fmaf(r, cv1[k], d1);
      d2 = fmaf(r, cv2[k], d2);
      d3 = fmaf(r, cv3[k], d3);
    }
    bool m0 = ((c + 0) >= climit) || (is_t && ((c0 + c + 0) == j));
    bool m1 = ((c + 1) >= climit) || (is_t && ((c0 + c + 1) == j));
    bool m2 = ((c + 2) >= climit) || (is_t && ((c0 + c + 2) == j));
    bool m3 = ((c + 3) >= climit) || (is_t && ((c0 + c + 3) == j));
    s += m0 ? 0.0f : __expf(d0 * 10.0f);
    s += m1 ? 0.0f : __expf(d1 * 10.0f);
    s += m2 ? 0.0f : __expf(d2 * 10.0f);
    s += m3 ? 0.0f : __expf(d3 * 10.0f);
  }
  atomicAdd(&wsf[(is_t ? FO_ST : FO_SO) + j], s);
}

// K7: single block: tiny loss reduce + cls contrastive + final assembly
__global__ __launch_bounds__(256) void k_final(const float* __restrict__ emb,
                                               const int* __restrict__ clst,
                                               const float* __restrict__ wsf,
                                               const int* __restrict__ wsi,
                                               float* __restrict__ out) {
  __shared__ float e[8 * 256];
  __shared__ float sdot[64];
  __shared__ float sred[4];
  __shared__ float s_pera[8];
  __shared__ int s_val[8];
  __shared__ float s_bce[8];
  int tid = threadIdx.x;

  // tiny loss: per[j] = log(st+so) - log(st), summed over valid rows
  int cnt = wsi[IO_SCAL + 0];
  int vt = cnt < MAXT ? cnt : MAXT;
  float ts = 0.0f;
  for (int jj = tid; jj < vt; jj += 256) {
    float a = wsf[FO_ST + jj];
    float c2 = wsf[FO_SO + jj];
    ts += __logf(a + c2) - __logf(a);
  }
  ts = wave_sum(ts);
  if ((tid & 63) == 0) sred[tid >> 6] = ts;
  __syncthreads();

  // cls embeddings: load + normalize
  for (int k = tid; k < 2048; k += 256) e[k] = emb[k];
  __syncthreads();
  int row = tid >> 5, lane = tid & 31;
  float ss = 0.0f;
  for (int k = lane; k < 256; k += 32) { float v = e[row * 256 + k]; ss += v * v; }
  #pragma unroll
  for (int off = 16; off > 0; off >>= 1) ss += __shfl_xor(ss, off, 32);
  float invn = 1.0f / fmaxf(sqrtf(ss), 1e-12f);
  for (int k = lane; k < 256; k += 32) e[row * 256 + k] *= invn;
  __syncthreads();
  if (tid < 64) {
    int i = tid >> 3, jc = tid & 7;
    float d = 0.0f;
    for (int k = 0; k < 256; k++) d = fmaf(e[i * 256 + k], e[jc * 256 + k], d);
    sdot[tid] = d;
  }
  __syncthreads();
  if (tid < 8) {
    int li = clst[tid];
    float spos = 0.0f, sall = 0.0f, bce = 0.0f;
    int haspos = 0;
    for (int jc = 0; jc < 8; jc++) {
      if (jc == tid) continue;
      float d = sdot[tid * 8 + jc];
      float ex = __expf(d * 10.0f);
      sall += ex;
      int same = (clst[jc] == li) ? 1 : 0;
      if (same) { spos += ex; haspos = 1; }
      float cosv = fminf(fmaxf(d, -1.0f), 1.0f);
      float p01 = (cosv + 1.0f) * 0.5f;
      float lpv = fmaxf(__logf(p01), -100.0f);
      float lnv = fmaxf(__logf(1.0f - p01), -100.0f);
      bce += -(same ? lpv : lnv);
    }
    s_pera[tid] = __logf(sall) - __logf(spos);  // -(lse_pos - lse_all)
    s_val[tid] = haspos;
    s_bce[tid] = bce;
  }
  __syncthreads();
  if (tid == 0) {
    int nv = 0;
    float sm = 0.0f, sb = 0.0f;
    for (int i = 0; i < 8; i++) {
      if (s_val[i]) { nv++; sm += s_pera[i]; }
      sb += s_bce[i];
    }
    float cls = (nv > 0) ? (sm / (float)nv) : (sb / 56.0f);
    float invN = 1.0f / (float)NPIX;
    float ce_l = wsf[0] * invN;
    float focal_l = wsf[1] * invN;
    float grad_l = wsf[2] * invN;
    float dsum = 0.0f;
    for (int c = 0; c < 5; c++)
      dsum += (2.0f * wsf[3 + c] + 1e-6f) / (wsf[8 + c] + wsf[13 + c] + 1e-6f);
    float dice_l = 1.0f - dsum * 0.2f;
    int anyt = wsi[IO_SCAL + 1];
    bool enabled = (anyt != 0) && (cnt >= 16);   // MIN_TINY
    float tiny_total = sred[0] + sred[1] + sred[2] + sred[3];
    int n_t = vt > 1 ? vt : 1;
    float tiny_l = enabled ? (tiny_total / (float)n_t) : 0.0f;
    out[0] = ce_l + dice_l + focal_l + grad_l + tiny_l + cls;
  }
}

extern "C" void kernel_launch(void* const* d_in, const int* in_sizes, int n_in,
                              void* d_out, int out_size, void* d_ws, size_t ws_size,
                              hipStream_t stream) {
  (void)in_sizes; (void)n_in; (void)out_size; (void)ws_size;
  const float* logits = (const float*)d_in[0];
  const int* targets = (const int*)d_in[1];
  const float* pf = (const float*)d_in[2];
  const float* emb = (const float*)d_in[3];
  const int* clst = (const int*)d_in[4];
  float* out = (float*)d_out;
  float* wsf = (float*)d_ws;
  int* wsi = (int*)d_ws;

  hipMemsetAsync(d_ws, 0, Z_ELEMS * 4, stream);
  hipLaunchKernelGGL(k_main, dim3(NBLK), dim3(256), 0, stream, logits, targets, wsf, wsi);
  hipLaunchKernelGGL(k_sobel, dim3(NBLK), dim3(256), 0, stream, targets, wsf + FO_PRED, wsf);
  hipLaunchKernelGGL(k_scan, dim3(1), dim3(256), 0, stream, wsi, wsf);
  hipLaunchKernelGGL(k_widx, dim3(NROWS), dim3(512), 0, stream, targets, wsi);
  hipLaunchKernelGGL(k_gather, dim3(5120 / 8), dim3(256), 0, stream, pf, wsi, wsf);
  hipLaunchKernelGGL(k_sim, dim3(320), dim3(256), 0, stream, wsf, wsi);
  hipLaunchKernelGGL(k_final, dim3(1), dim3(256), 0, stream, emb, clst, wsf, wsi, out);
}

// Round 4
// 381.718 us; speedup vs baseline: 1.5463x; 1.0281x over previous
//
#include <hip/hip_runtime.h>
#include <hip/hip_bf16.h>
#include <math.h>

// Problem constants (fixed by setup_inputs)
#define Bq   8
#define Cc   5
#define Hh   512
#define Ww   512
#define HW   262144      // 512*512
#define NPIX 2097152     // 8*HW
#define CF   32
#define NROWS 4096       // B*H
#define MAXT 1024
#define MAXO 4096
#define NBLKM 2048       // k_main grid: NPIX/4/256
#define NBLKS 1024       // k_sobel grid: NROWS/4

// ws layout, element offsets (4-byte units). Region [0, Z_ELEMS) is zeroed each launch.
#define FO_ACC    0        // 18 floats: [0]ce [1]focal [2]grad [3..7]inter [8..12]psum [13..17]cnt
#define IO_ROWCNT 32       // int[4096] fg count per image-row
#define FO_ST     4128     // float[1024] sum exp(sim_t) per tiny row
#define FO_SO     5152     // float[1024] sum exp(sim_o) per tiny row
#define Z_ELEMS   6176
#define IO_PREFIX 6176     // int[4096] exclusive prefix of tiny counts per row
#define IO_SCAL   10272    // int[16]: [0]=cnt_tiny [1]=any_tiny [2..9]=tiny_img flags
#define IO_TIDX   10288    // int[1024]
#define IO_OIDX   11312    // int[4096]
#define FO_TEMB   15408    // float[1024*32]
#define FO_OEMB   48176    // float[4096*32]
#define FO_PART   179248   // float[18*2048]  per-block partials from k_main ([k][blk])
#define FO_GPART  216112   // float[1024]     per-block partials from k_sobel
#define FO_PRED   217136   // float[NPIX]
#define WS_ELEMS  2314288  // ~9.26 MB

__device__ __forceinline__ float wave_sum(float v) {
  #pragma unroll
  for (int off = 32; off > 0; off >>= 1) v += __shfl_xor(v, off);
  return v;
}

// K1: per-pixel softmax, 4 px/thread via float4 -> ce, focal, dice partials,
// pred_fg, per-row fg counts. Per-block partials stored; reduced in k_scan.
__global__ __launch_bounds__(256) void k_main(const float* __restrict__ logits,
                                              const int* __restrict__ targets,
                                              float* __restrict__ wsf,
                                              int* __restrict__ wsi) {
  int tid = threadIdx.x;
  int idx = (blockIdx.x * 256 + tid) << 2;
  int b = idx >> 18;
  int rem = idx & (HW - 1);
  const float* lp = logits + (size_t)b * (Cc * HW) + rem;
  float4 c0 = *(const float4*)(lp);
  float4 c1 = *(const float4*)(lp + HW);
  float4 c2 = *(const float4*)(lp + 2 * HW);
  float4 c3 = *(const float4*)(lp + 3 * HW);
  float4 c4 = *(const float4*)(lp + 4 * HW);
  int4 ti = *(const int4*)(targets + idx);
  float l[5][4] = {{c0.x, c0.y, c0.z, c0.w},
                   {c1.x, c1.y, c1.z, c1.w},
                   {c2.x, c2.y, c2.z, c2.w},
                   {c3.x, c3.y, c3.z, c3.w},
                   {c4.x, c4.y, c4.z, c4.w}};
  int ta[4] = {ti.x, ti.y, ti.z, ti.w};
  float acc[18];
  #pragma unroll
  for (int k = 0; k < 18; k++) acc[k] = 0.0f;
  float pout[4];
  int fgc = 0;
  #pragma unroll
  for (int px = 0; px < 4; px++) {
    float l0 = l[0][px], l1 = l[1][px], l2 = l[2][px], l3 = l[3][px], l4 = l[4][px];
    float m = fmaxf(fmaxf(fmaxf(l0, l1), fmaxf(l2, l3)), l4);
    float e0 = __expf(l0 - m), e1 = __expf(l1 - m), e2 = __expf(l2 - m),
          e3 = __expf(l3 - m), e4 = __expf(l4 - m);
    float se = e0 + e1 + e2 + e3 + e4;
    float inv = 1.0f / se;
    float p0 = e0 * inv, p1 = e1 * inv, p2 = e2 * inv, p3 = e3 * inv, p4 = e4 * inv;
    int t = ta[px];
    float lt = t == 0 ? l0 : t == 1 ? l1 : t == 2 ? l2 : t == 3 ? l3 : l4;
    float pt = t == 0 ? p0 : t == 1 ? p1 : t == 2 ? p2 : t == 3 ? p3 : p4;
    float ce = __logf(se) + m - lt;                 // -log_softmax[target]
    float om = fminf(fmaxf(1.0f - pt, 0.0f), 1.0f);
    pout[px] = p1;
    fgc += (t == 1) ? 1 : 0;
    acc[0] += ce; acc[1] += om * om * ce;
    acc[3] += (t == 0) ? pt : 0.0f;
    acc[4] += (t == 1) ? pt : 0.0f;
    acc[5] += (t == 2) ? pt : 0.0f;
    acc[6] += (t == 3) ? pt : 0.0f;
    acc[7] += (t == 4) ? pt : 0.0f;
    acc[8] += p0; acc[9] += p1; acc[10] += p2; acc[11] += p3; acc[12] += p4;
    acc[13] += (t == 0) ? 1.0f : 0.0f;
    acc[14] += (t == 1) ? 1.0f : 0.0f;
    acc[15] += (t == 2) ? 1.0f : 0.0f;
    acc[16] += (t == 3) ? 1.0f : 0.0f;
    acc[17] += (t == 4) ? 1.0f : 0.0f;
  }
  float4 po = {pout[0], pout[1], pout[2], pout[3]};
  *(float4*)(wsf + FO_PRED + idx) = po;
  // a wave's 256 consecutive px (256-aligned) sit in one 512-wide row
  #pragma unroll
  for (int off = 32; off > 0; off >>= 1) fgc += __shfl_xor(fgc, off);
  int lane = tid & 63, wv = tid >> 6;
  if (lane == 0 && fgc) atomicAdd(&wsi[IO_ROWCNT + (idx >> 9)], fgc);

  __shared__ float red[4][18];
  #pragma unroll
  for (int k = 0; k < 18; k++) acc[k] = wave_sum(acc[k]);
  if (lane == 0) {
    #pragma unroll
    for (int k = 0; k < 18; k++) red[wv][k] = acc[k];
  }
  __syncthreads();
  if (tid < 18) {
    float s = red[0][tid] + red[1][tid] + red[2][tid] + red[3][tid];
    wsf[FO_PART + tid * NBLKM + blockIdx.x] = s;
  }
}

// K2: Sobel |grad(pred_fg) - grad(target_fg)|, 8 px/thread, register rows.
// 24 mem insts per 8 px instead of 144.
__global__ __launch_bounds__(256) void k_sobel(const int* __restrict__ targets,
                                               const float* __restrict__ pred,
                                               float* __restrict__ wsf) {
  int tid = threadIdx.x;
  int h = blockIdx.x * 4 + (tid >> 6);   // global row 0..4095
  int w0 = (tid & 63) << 3;              // 8-px segment start
  int b = h >> 9, hl = h & 511;
  const float* pb = pred + (size_t)b * HW;
  const int* tb = targets + (size_t)b * HW;
  float P[3][10], T[3][10];
  #pragma unroll
  for (int r = 0; r < 3; r++) {
    int hr = hl + r - 1;
    bool v = (hr >= 0) & (hr < Hh);
    if (v) {
      int base = (hr << 9) + w0;
      float4 a = *(const float4*)(pb + base);
      float4 bb = *(const float4*)(pb + base + 4);
      P[r][1] = a.x;  P[r][2] = a.y;  P[r][3] = a.z;  P[r][4] = a.w;
      P[r][5] = bb.x; P[r][6] = bb.y; P[r][7] = bb.z; P[r][8] = bb.w;
      P[r][0] = (w0 > 0)   ? pb[base - 1] : 0.0f;
      P[r][9] = (w0 < 504) ? pb[base + 8] : 0.0f;
      int4 u = *(const int4*)(tb + base);
      int4 w = *(const int4*)(tb + base + 4);
      T[r][1] = (u.x > 0) ? 1.0f : 0.0f; T[r][2] = (u.y > 0) ? 1.0f : 0.0f;
      T[r][3] = (u.z > 0) ? 1.0f : 0.0f; T[r][4] = (u.w > 0) ? 1.0f : 0.0f;
      T[r][5] = (w.x > 0) ? 1.0f : 0.0f; T[r][6] = (w.y > 0) ? 1.0f : 0.0f;
      T[r][7] = (w.z > 0) ? 1.0f : 0.0f; T[r][8] = (w.w > 0) ? 1.0f : 0.0f;
      T[r][0] = (w0 > 0   && tb[base - 1] > 0) ? 1.0f : 0.0f;
      T[r][9] = (w0 < 504 && tb[base + 8] > 0) ? 1.0f : 0.0f;
    } else {
      #pragma unroll
      for (int c = 0; c < 10; c++) { P[r][c] = 0.0f; T[r][c] = 0.0f; }
    }
  }
  float s = 0.0f;
  #pragma unroll
  for (int px = 0; px < 8; px++) {
    float gxp = (P[0][px + 2] - P[0][px]) + 2.0f * (P[1][px + 2] - P[1][px]) +
                (P[2][px + 2] - P[2][px]);
    float gyp = (P[2][px] + 2.0f * P[2][px + 1] + P[2][px + 2]) -
                (P[0][px] + 2.0f * P[0][px + 1] + P[0][px + 2]);
    float gp = sqrtf(gxp * gxp + gyp * gyp + 1e-6f);
    float gxt = (T[0][px + 2] - T[0][px]) + 2.0f * (T[1][px + 2] - T[1][px]) +
                (T[2][px + 2] - T[2][px]);
    float gyt = (T[2][px] + 2.0f * T[2][px + 1] + T[2][px + 2]) -
                (T[0][px] + 2.0f * T[0][px + 1] + T[0][px + 2]);
    float gt = sqrtf(gxt * gxt + gyt * gyt + 1e-6f);
    s += fabsf(gp - gt);
  }
  s = wave_sum(s);
  __shared__ float red[4];
  int lane = tid & 63, wv = tid >> 6;
  if (lane == 0) red[wv] = s;
  __syncthreads();
  if (tid == 0) wsf[FO_GPART + blockIdx.x] = red[0] + red[1] + red[2] + red[3];
}

// K3: single block: reduce k_main/k_sobel partials; tiny_img flags; exclusive
// prefix of tiny counts over 4096 rows
__global__ __launch_bounds__(256) void k_scan(int* __restrict__ wsi,
                                              float* __restrict__ wsf) {
  __shared__ int ssum[256];
  __shared__ int stimg[8];
  __shared__ int sc[256];
  __shared__ float fred[4][18];
  __shared__ float gred[4];
  int tid = threadIdx.x;
  int lane = tid & 63, wv = tid >> 6;

  // --- reduce the 18 k_main partial arrays (2048 each) + sobel partials (1024) ---
  float ls[18];
  #pragma unroll
  for (int k = 0; k < 18; k++) {
    const float* p = wsf + FO_PART + k * NBLKM + tid;
    float v = 0.0f;
    #pragma unroll
    for (int i = 0; i < 8; i++) v += p[i * 256];
    ls[k] = v;
  }
  #pragma unroll
  for (int k = 0; k < 18; k++) ls[k] = wave_sum(ls[k]);
  if (lane == 0) {
    #pragma unroll
    for (int k = 0; k < 18; k++) fred[wv][k] = ls[k];
  }
  {
    const float* p = wsf + FO_GPART + tid;
    float g = p[0] + p[256] + p[512] + p[768];
    g = wave_sum(g);
    if (lane == 0) gred[wv] = g;
  }
  __syncthreads();
  if (tid < 18) {
    float s = fred[0][tid] + fred[1][tid] + fred[2][tid] + fred[3][tid];
    if (tid == 2) s = gred[0] + gred[1] + gred[2] + gred[3];
    wsf[FO_ACC + tid] = s;
  }

  // --- row scan ---
  int base = tid * 16;          // thread covers rows [base, base+16), within one image
  int loc[16];
  int s = 0;
  #pragma unroll
  for (int k = 0; k < 16; k++) { loc[k] = wsi[IO_ROWCNT + base + k]; s += loc[k]; }
  ssum[tid] = s;
  __syncthreads();
  if (tid < 8) {
    int tot = 0;
    for (int u = 0; u < 32; u++) tot += ssum[tid * 32 + u];
    stimg[tid] = (tot > 0 && tot <= 2048) ? 1 : 0;   // TINY_THRESH
  }
  __syncthreads();
  int timg = stimg[tid >> 5];
  int ms = timg ? s : 0;
  sc[tid] = ms;
  __syncthreads();
  for (int off = 1; off < 256; off <<= 1) {
    int add = (tid >= off) ? sc[tid - off] : 0;
    __syncthreads();
    sc[tid] += add;
    __syncthreads();
  }
  int run = sc[tid] - ms;       // exclusive prefix at this thread's first row
  #pragma unroll
  for (int k = 0; k < 16; k++) {
    wsi[IO_PREFIX + base + k] = run;
    run += timg ? loc[k] : 0;
  }
  if (tid == 255) wsi[IO_SCAL + 0] = sc[255];
  if (tid < 8) wsi[IO_SCAL + 2 + tid] = stimg[tid];
  if (tid == 0) {
    int anyf = 0;
    for (int u = 0; u < 8; u++) anyf |= stimg[u];
    wsi[IO_SCAL + 1] = anyf;
  }
}

// K4: ordered compaction — first MAXT tiny indices, first MAXO non-tiny indices
__global__ __launch_bounds__(512) void k_widx(const int* __restrict__ targets,
                                              int* __restrict__ wsi) {
  int r = blockIdx.x;
  int tid = threadIdx.x;
  int b = r >> 9;
  int timg = wsi[IO_SCAL + 2 + b];
  int trc = timg ? wsi[IO_ROWCNT + r] : 0;
  int p = wsi[IO_PREFIX + r];
  int q = (r << 9) - p;   // false count before this row
  bool need_t = (trc > 0) && (p < MAXT);
  bool need_o = (q < MAXO) && (trc < 512);
  if (!need_t && !need_o) return;
  int i = (r << 9) + tid;
  int t = targets[i];
  bool f = (timg != 0) && (t == 1);
  unsigned long long mask = __ballot(f ? 1 : 0);
  int lane = tid & 63, wv = tid >> 6;
  int lpfx = __popcll(mask & ((1ull << lane) - 1ull));
  __shared__ int wt[8];
  if (lane == 0) wt[wv] = __popcll(mask);
  __syncthreads();
  int woff = 0;
  for (int u = 0; u < wv; u++) woff += wt[u];
  int local = woff + lpfx;
  if (f) {
    int pos = p + local;
    if (pos < MAXT) wsi[IO_TIDX + pos] = i;
  } else {
    int fpos = q + (tid - local);
    if (fpos < MAXO) wsi[IO_OIDX + fpos] = i;
  }
}

// K5: gather + L2-normalize 32-dim feature rows (1024 tiny + 4096 other)
__global__ __launch_bounds__(256) void k_gather(const float* __restrict__ pf,
                                                const int* __restrict__ wsi,
                                                float* __restrict__ wsf) {
  int tid = threadIdx.x;
  int g = blockIdx.x * 8 + (tid >> 5);
  int lane = tid & 31;
  int cnt = wsi[IO_SCAL + 0];
  int cnt_t = cnt < MAXT ? cnt : MAXT;
  long cfal = (long)NPIX - (long)cnt;
  int cnt_o = cfal > MAXO ? MAXO : (int)cfal;
  int idx;
  float* dst;
  if (g < MAXT) {
    dst = wsf + FO_TEMB + (size_t)g * 32;
    idx = (g < cnt_t) ? wsi[IO_TIDX + g] : -1;
  } else {
    int go = g - MAXT;
    dst = wsf + FO_OEMB + (size_t)go * 32;
    idx = (go < cnt_o) ? wsi[IO_OIDX + go] : -1;
  }
  float v = 0.0f;
  if (idx >= 0) {
    int b = idx >> 18;
    int rem = idx & (HW - 1);
    v = pf[((size_t)b * CF + lane) * HW + rem];
  }
  float ss = v * v;
  #pragma unroll
  for (int off = 16; off > 0; off >>= 1) ss += __shfl_xor(ss, off, 32);
  float nrm = fmaxf(sqrtf(ss), 1e-12f);
  dst[lane] = v / nrm;
}

// K6: sim rows (1024) x cols (1024 t + 4096 o); plain-sum logsumexp partials.
// sim in [-10,10] since vectors are unit-norm, so exp() is safe without max-shift.
// 4-col unroll: 4 independent FMA chains, 512 B of uniform loads in flight.
__global__ __launch_bounds__(256) void k_sim(float* __restrict__ wsf,
                                             const int* __restrict__ wsi) {
  int tid = threadIdx.x;
  int rb = blockIdx.x / 80;   // 0..3 row blocks of 256
  int cc = blockIdx.x % 80;   // 0..79 col chunks of 64
  int j = rb * 256 + tid;
  const float* temb = wsf + FO_TEMB;
  const float* oemb = wsf + FO_OEMB;
  float rv[32];
  const float4* r4 = (const float4*)(temb + (size_t)j * 32);
  #pragma unroll
  for (int k = 0; k < 8; k++) {
    float4 x = r4[k];
    rv[4 * k + 0] = x.x; rv[4 * k + 1] = x.y; rv[4 * k + 2] = x.z; rv[4 * k + 3] = x.w;
  }
  int cnt = wsi[IO_SCAL + 0];
  int cnt_t = cnt < MAXT ? cnt : MAXT;
  long cfal = (long)NPIX - (long)cnt;
  int cnt_o = cfal > MAXO ? MAXO : (int)cfal;
  int c0 = cc * 64;
  bool is_t = (c0 < MAXT);
  const float* cbase = is_t ? (temb + (size_t)c0 * 32) : (oemb + (size_t)(c0 - MAXT) * 32);
  int climit = is_t ? (cnt_t - c0) : (cnt_o - (c0 - MAXT));
  float s = 0.0f;
  for (int c = 0; c < 64; c += 4) {
    const float* cv0 = cbase + (c + 0) * 32;
    const float* cv1 = cbase + (c + 1) * 32;
    const float* cv2 = cbase + (c + 2) * 32;
    const float* cv3 = cbase + (c + 3) * 32;
    float d0 = 0.0f, d1 = 0.0f, d2 = 0.0f, d3 = 0.0f;
    #pragma unroll
    for (int k = 0; k < 32; k++) {
      float r = rv[k];
      d0 = fmaf(r, cv0[k], d0);
      d1 = fmaf(r, cv1[k], d1);
      d2 = fmaf(r, cv2[k], d2);
      d3 = fmaf(r, cv3[k], d3);
    }
    bool m0 = ((c + 0) >= climit) || (is_t && ((c0 + c + 0) == j));
    bool m1 = ((c + 1) >= climit) || (is_t && ((c0 + c + 1) == j));
    bool m2 = ((c + 2) >= climit) || (is_t && ((c0 + c + 2) == j));
    bool m3 = ((c + 3) >= climit) || (is_t && ((c0 + c + 3) == j));
    s += m0 ? 0.0f : __expf(d0 * 10.0f);
    s += m1 ? 0.0f : __expf(d1 * 10.0f);
    s += m2 ? 0.0f : __expf(d2 * 10.0f);
    s += m3 ? 0.0f : __expf(d3 * 10.0f);
  }
  atomicAdd(&wsf[(is_t ? FO_ST : FO_SO) + j], s);
}

// K7: single block: tiny loss reduce + cls contrastive + final assembly
__global__ __launch_bounds__(256) void k_final(const float* __restrict__ emb,
                                               const int* __restrict__ clst,
                                               const float* __restrict__ wsf,
                                               const int* __restrict__ wsi,
                                               float* __restrict__ out) {
  __shared__ float e[8 * 256];
  __shared__ float sdot[64];
  __shared__ float sred[4];
  __shared__ float s_pera[8];
  __shared__ int s_val[8];
  __shared__ float s_bce[8];
  int tid = threadIdx.x;

  // tiny loss: per[j] = log(st+so) - log(st), summed over valid rows
  int cnt = wsi[IO_SCAL + 0];
  int vt = cnt < MAXT ? cnt : MAXT;
  float ts = 0.0f;
  for (int jj = tid; jj < vt; jj += 256) {
    float a = wsf[FO_ST + jj];
    float c2 = wsf[FO_SO + jj];
    ts += __logf(a + c2) - __logf(a);
  }
  ts = wave_sum(ts);
  if ((tid & 63) == 0) sred[tid >> 6] = ts;
  __syncthreads();

  // cls embeddings: load + normalize
  for (int k = tid; k < 2048; k += 256) e[k] = emb[k];
  __syncthreads();
  int row = tid >> 5, lane = tid & 31;
  float ss = 0.0f;
  for (int k = lane; k < 256; k += 32) { float v = e[row * 256 + k]; ss += v * v; }
  #pragma unroll
  for (int off = 16; off > 0; off >>= 1) ss += __shfl_xor(ss, off, 32);
  float invn = 1.0f / fmaxf(sqrtf(ss), 1e-12f);
  for (int k = lane; k < 256; k += 32) e[row * 256 + k] *= invn;
  __syncthreads();
  if (tid < 64) {
    int i = tid >> 3, jc = tid & 7;
    float d = 0.0f;
    for (int k = 0; k < 256; k++) d = fmaf(e[i * 256 + k], e[jc * 256 + k], d);
    sdot[tid] = d;
  }
  __syncthreads();
  if (tid < 8) {
    int li = clst[tid];
    float spos = 0.0f, sall = 0.0f, bce = 0.0f;
    int haspos = 0;
    for (int jc = 0; jc < 8; jc++) {
      if (jc == tid) continue;
      float d = sdot[tid * 8 + jc];
      float ex = __expf(d * 10.0f);
      sall += ex;
      int same = (clst[jc] == li) ? 1 : 0;
      if (same) { spos += ex; haspos = 1; }
      float cosv = fminf(fmaxf(d, -1.0f), 1.0f);
      float p01 = (cosv + 1.0f) * 0.5f;
      float lpv = fmaxf(__logf(p01), -100.0f);
      float lnv = fmaxf(__logf(1.0f - p01), -100.0f);
      bce += -(same ? lpv : lnv);
    }
    s_pera[tid] = __logf(sall) - __logf(spos);  // -(lse_pos - lse_all)
    s_val[tid] = haspos;
    s_bce[tid] = bce;
  }
  __syncthreads();
  if (tid == 0) {
    int nv = 0;
    float sm = 0.0f, sb = 0.0f;
    for (int i = 0; i < 8; i++) {
      if (s_val[i]) { nv++; sm += s_pera[i]; }
      sb += s_bce[i];
    }
    float cls = (nv > 0) ? (sm / (float)nv) : (sb / 56.0f);
    float invN = 1.0f / (float)NPIX;
    float ce_l = wsf[0] * invN;
    float focal_l = wsf[1] * invN;
    float grad_l = wsf[2] * invN;
    float dsum = 0.0f;
    for (int c = 0; c < 5; c++)
      dsum += (2.0f * wsf[3 + c] + 1e-6f) / (wsf[8 + c] + wsf[13 + c] + 1e-6f);
    float dice_l = 1.0f - dsum * 0.2f;
    int anyt = wsi[IO_SCAL + 1];
    bool enabled = (anyt != 0) && (cnt >= 16);   // MIN_TINY
    float tiny_total = sred[0] + sred[1] + sred[2] + sred[3];
    int n_t = vt > 1 ? vt : 1;
    float tiny_l = enabled ? (tiny_total / (float)n_t) : 0.0f;
    out[0] = ce_l + dice_l + focal_l + grad_l + tiny_l + cls;
  }
}

extern "C" void kernel_launch(void* const* d_in, const int* in_sizes, int n_in,
                              void* d_out, int out_size, void* d_ws, size_t ws_size,
                              hipStream_t stream) {
  (void)in_sizes; (void)n_in; (void)out_size; (void)ws_size;
  const float* logits = (const float*)d_in[0];
  const int* targets = (const int*)d_in[1];
  const float* pf = (const float*)d_in[2];
  const float* emb = (const float*)d_in[3];
  const int* clst = (const int*)d_in[4];
  float* out = (float*)d_out;
  float* wsf = (float*)d_ws;
  int* wsi = (int*)d_ws;

  hipMemsetAsync(d_ws, 0, Z_ELEMS * 4, stream);
  hipLaunchKernelGGL(k_main, dim3(NBLKM), dim3(256), 0, stream, logits, targets, wsf, wsi);
  hipLaunchKernelGGL(k_sobel, dim3(NBLKS), dim3(256), 0, stream, targets, wsf + FO_PRED, wsf);
  hipLaunchKernelGGL(k_scan, dim3(1), dim3(256), 0, stream, wsi, wsf);
  hipLaunchKernelGGL(k_widx, dim3(NROWS), dim3(512), 0, stream, targets, wsi);
  hipLaunchKernelGGL(k_gather, dim3(5120 / 8), dim3(256), 0, stream, pf, wsi, wsf);
  hipLaunchKernelGGL(k_sim, dim3(320), dim3(256), 0, stream, wsf, wsi);
  hipLaunchKernelGGL(k_final, dim3(1), dim3(256), 0, stream, emb, clst, wsf, wsi, out);
}